// Round 13
// baseline (7297.639 us; speedup 1.0000x reference)
//
#include <hip/hip_runtime.h>
#include <math.h>

// Fixed instance constants.
#define Nn 4096          // n = m * tmax
#define BSc 32           // batch size (border rows)
#define NB 128           // block size
#define NBP 132          // padded LDS row stride (16B-aligned rows)
#define NBB 32           // sub-block for recursive factorization
#define NBLK 33          // block-rows: 32 full + 1 border (32 rows)
#define NK 32            // factorization steps
#define TILE_ELEMS (NB * NB)
#define NTILES 561       // NBLK*(NBLK+1)/2 lower tiles

// Fused-syrk LDS overlay: union of {4x bf16 staging tiles = 40960B} and
// {T[128][132] fp32 = 67584B}.
#define SM_SIZE 67584

typedef float f32x4 __attribute__((ext_vector_type(4)));
typedef short bf16x8 __attribute__((ext_vector_type(8)));

// Packed lower-block-triangular storage: tile(i,j), 0<=j<=i<=32.
__device__ __forceinline__ size_t tile_off(int i, int j) {
  return ((size_t)(j * NBLK - (j * (j - 1)) / 2 + (i - j))) * TILE_ELEMS;
}

// fp32 -> bf16 (round-to-nearest-even).
__device__ __forceinline__ unsigned short f2bf(float f) {
  union { float f; unsigned int u; } v; v.f = f;
  unsigned int r = v.u + 0x7fffu + ((v.u >> 16) & 1u);
  return (unsigned short)(r >> 16);
}
__device__ __forceinline__ float bf2f(unsigned short b) {
  union { unsigned int u; float f; } v; v.u = ((unsigned int)b) << 16;
  return v.f;
}

// ---------------------------------------------------------------------------
// prep: fill stored tiles from the virtual bordered matrix. (r2..r12-proven)
// ---------------------------------------------------------------------------
__global__ __launch_bounds__(256) void prep(const float* __restrict__ Y,
                                            const float* __restrict__ mu,
                                            const float* __restrict__ Kp,
                                            const float* __restrict__ Sg,
                                            float* __restrict__ W) {
  int bid = blockIdx.x;
  int j = 0;
  while (j + 1 < NBLK) {
    int nxt = (j + 1) * NBLK - ((j + 1) * j) / 2;
    if (bid < nxt) break;
    ++j;
  }
  int start = j * NBLK - (j * (j - 1)) / 2;
  int i = j + (bid - start);
  float* T = W + tile_off(i, j);
  int tid = threadIdx.x;
  for (int idx = tid; idx < TILE_ELEMS; idx += 256) {
    int li = idx >> 7, lj = idx & 127;
    int gr = i * NB + li, gc = j * NB + lj;
    float v = 0.0f;
    if (gr < Nn) {
      v = Kp[(size_t)gr * Nn + gc];
      if (gr == gc) v += Sg[(size_t)gr * Nn + gr];
    } else {
      int b = gr - Nn;
      if (b < BSc && gc < Nn) v = mu[gc] - Y[(size_t)b * Nn + gc];
    }
    T[idx] = v;
  }
}

// ---------------------------------------------------------------------------
// factor_lds: factor the 128x128 SPD tile in T (LDS).
//  A: Crout register Cholesky per 32-block (r4..r12-proven) + inv32
//     (r8-proven; U rows carry EXACT zeros above the diagonal). U is written
//     to global Uinv (for trsm) and stashed in T's unused upper triangle
//     (rows o..o+31, cols o+32..o+63) for the B-phase (kb<3 only).
//  B: trailing-row solve as branch-free float4 GEMM vs stashed U (no chain).
//  C: float4 trailing rank-32 update (r11/r12-proven).
// ---------------------------------------------------------------------------
__device__ __forceinline__ void factor_lds(float (*T)[NBP],
                                           float* __restrict__ Uinv, int tid) {
  int lane = tid & 63, wid = tid >> 6;
#pragma unroll 1
  for (int kb = 0; kb < 4; ++kb) {
    int o = kb * NBB;
    if (wid == 0) {
      int ii = lane & 31;
      // --- Crout chol32 (proven) ---
      float cc[NBB];
#pragma unroll
      for (int p = 0; p < NBB; ++p) cc[p] = T[o + ii][o + p];
#pragma unroll
      for (int j = 0; j < NBB; ++j) {
        float s = cc[j];
#pragma unroll
        for (int p = 0; p < NBB; ++p) {
          if (p < j) s -= cc[p] * __shfl(cc[p], j, 64);
        }
        float sj = __shfl(s, j, 64);
        float d = sqrtf(sj);
        if (ii == j) cc[j] = d;
        else if (ii > j) cc[j] = s / d;
      }
      if (lane < 32) {
#pragma unroll
        for (int p = 0; p < NBB; ++p) {
          if (p <= ii) T[o + ii][o + p] = cc[p];
        }
      }
      // --- inv32 (r8-proven): V = L^{-1}, exact zeros above diag ---
      float v[NBB];
#pragma unroll
      for (int p = 0; p < NBB; ++p) v[p] = (p == ii) ? 1.0f : 0.0f;
#pragma unroll
      for (int q = 0; q < NBB; ++q) {
        if (ii == q) {
          float dq = 1.0f / cc[q];
#pragma unroll
          for (int p = 0; p < NBB; ++p) v[p] *= dq;
        }
#pragma unroll
        for (int p = 0; p < NBB; ++p) {
          float vq = __shfl(v[p], q, 64);
          if (ii > q) v[p] -= cc[q] * vq;
        }
      }
      if (lane < 32) {
#pragma unroll
        for (int p4 = 0; p4 < 8; ++p4) {
          float4 w; w.x = v[p4 * 4]; w.y = v[p4 * 4 + 1];
          w.z = v[p4 * 4 + 2]; w.w = v[p4 * 4 + 3];
          *(float4*)&Uinv[kb * 1024 + ii * NBB + p4 * 4] = w;   // for trsm
        }
        if (kb < 3) {
#pragma unroll
          for (int p = 0; p < NBB; ++p) T[o + ii][o + NBB + p] = v[p];  // stash
        }
      }
    }
    __syncthreads();
    int R = NB - o - NBB;   // trailing rows: 96, 64, 32, 0
    if (R > 0) {
      // --- B: trailing-row solve as branch-free GEMM vs stashed U ---
      if (tid < R) {
        int r = o + NBB + tid;
        float4 xo4[8];
#pragma unroll
        for (int p4 = 0; p4 < 8; ++p4) xo4[p4] = *(const float4*)&T[r][o + p4 * 4];
        float xn[NBB];
#pragma unroll
        for (int c = 0; c < NBB; ++c) {
          float s = 0.0f;
#pragma unroll
          for (int p4 = 0; p4 < 8; ++p4) {
            float4 u4 = *(const float4*)&T[o + c][o + NBB + p4 * 4];
            s += xo4[p4].x * u4.x + xo4[p4].y * u4.y + xo4[p4].z * u4.z + xo4[p4].w * u4.w;
          }
          xn[c] = s;
        }
#pragma unroll
        for (int c4 = 0; c4 < 8; ++c4) {
          float4 w; w.x = xn[c4 * 4]; w.y = xn[c4 * 4 + 1];
          w.z = xn[c4 * 4 + 2]; w.w = xn[c4 * 4 + 3];
          *(float4*)&T[r][o + c4 * 4] = w;
        }
      }
      __syncthreads();
      // --- C: trailing rank-32 update, lower 4x4 tiles, float4 (proven) ---
      int TL = R >> 2;
      int ntile = TL * (TL + 1) / 2;
#pragma unroll 1
      for (int t = tid; t < ntile; t += 256) {
        int ti = (int)((sqrtf(8.0f * t + 1.0f) - 1.0f) * 0.5f);
        while ((ti + 1) * (ti + 2) / 2 <= t) ++ti;
        while (ti * (ti + 1) / 2 > t) --ti;
        int tj = t - ti * (ti + 1) / 2;
        int tr = o + NBB + ti * 4, tc = o + NBB + tj * 4;
        float acc[4][4];
#pragma unroll
        for (int m = 0; m < 4; ++m)
#pragma unroll
          for (int n = 0; n < 4; ++n) acc[m][n] = 0.0f;
#pragma unroll
        for (int p4 = 0; p4 < 8; ++p4) {
          float4 a[4], b[4];
#pragma unroll
          for (int m = 0; m < 4; ++m) a[m] = *(const float4*)&T[tr + m][o + p4 * 4];
#pragma unroll
          for (int n = 0; n < 4; ++n) b[n] = *(const float4*)&T[tc + n][o + p4 * 4];
#pragma unroll
          for (int m = 0; m < 4; ++m)
#pragma unroll
            for (int n = 0; n < 4; ++n)
              acc[m][n] += a[m].x * b[n].x + a[m].y * b[n].y + a[m].z * b[n].z + a[m].w * b[n].w;
        }
#pragma unroll
        for (int m = 0; m < 4; ++m)
#pragma unroll
          for (int n = 0; n < 4; ++n) T[tr + m][tc + n] -= acc[m][n];
      }
    }
    __syncthreads();
  }
}

// ---------------------------------------------------------------------------
// potf2: one-shot factor of tile(0,0); writes Uinv for trsm(0).
// ---------------------------------------------------------------------------
__global__ __launch_bounds__(256) void potf2(float* __restrict__ W,
                                             float* __restrict__ Uinv, int k) {
  __shared__ __align__(16) unsigned char SMEM[SM_SIZE];
  float (*T)[NBP] = (float (*)[NBP])SMEM;
  float* G = W + tile_off(k, k);
  int tid = threadIdx.x;
  for (int idx = tid; idx < TILE_ELEMS / 4; idx += 256) {
    float4 v = ((const float4*)G)[idx];
    int r = idx >> 5, c = (idx & 31) * 4;
    *(float4*)&T[r][c] = v;
  }
  __syncthreads();
  factor_lds(T, Uinv, tid);
  for (int idx = tid; idx < TILE_ELEMS; idx += 256) {
    int i = idx >> 7, j = idx & 127;
    if (j <= i) G[idx] = T[i][j];
  }
}

// ---------------------------------------------------------------------------
// trsm: tile(i,k) <- tile(i,k) * L_kk^{-T}. jb off-diag float4 GEMM
// (r11/r12-proven) + inner solve as branch-free GEMM vs Uin (diag-block
// inverses from Uinv). Epilogue: split-bf16 panel store.
// ---------------------------------------------------------------------------
__global__ __launch_bounds__(256) void trsm(float* __restrict__ W,
                                            const float* __restrict__ Uinv,
                                            unsigned short* __restrict__ PH,
                                            unsigned short* __restrict__ PL,
                                            int k) {
  __shared__ float Td[NB][NBP];
  __shared__ float X[NB][NBP];
  __shared__ float Uin[4][NBB][NBB + 4];
  int tid = threadIdx.x;
  int i = k + 1 + blockIdx.x;
  int rows = (i == NBLK - 1) ? BSc : NB;
  const float* Gd = W + tile_off(k, k);
  const float* Gx = W + tile_off(i, k);
  for (int idx = tid; idx < TILE_ELEMS / 4; idx += 256) {
    float4 v = ((const float4*)Gd)[idx];
    float4 u = ((const float4*)Gx)[idx];
    int r = idx >> 5, c = (idx & 31) * 4;
    *(float4*)&Td[r][c] = v;
    if (r >= rows) { u.x = 0.0f; u.y = 0.0f; u.z = 0.0f; u.w = 0.0f; }
    *(float4*)&X[r][c] = u;
  }
  for (int v4 = tid; v4 < 1024; v4 += 256) {       // 4 blocks x 32 rows x 8 f4
    float4 u = *(const float4*)&Uinv[v4 * 4];
    int kb = v4 >> 8, rem = v4 & 255;
    int r = rem >> 3, c4 = rem & 7;
    *(float4*)&Uin[kb][r][c4 * 4] = u;
  }
  __syncthreads();
  int rtile = (tid >> 3) * 4;
  int ctile = (tid & 7) * 4;
#pragma unroll 1
  for (int jb = 0; jb < 4; ++jb) {
    int o = jb * NBB;
    if (jb > 0) {
      float acc[4][4];
#pragma unroll
      for (int m = 0; m < 4; ++m)
#pragma unroll
        for (int n = 0; n < 4; ++n) acc[m][n] = 0.0f;
#pragma unroll 1
      for (int p4 = 0; p4 < (o >> 2); ++p4) {
        float4 a[4], b[4];
#pragma unroll
        for (int m = 0; m < 4; ++m) a[m] = *(const float4*)&X[rtile + m][p4 * 4];
#pragma unroll
        for (int n = 0; n < 4; ++n) b[n] = *(const float4*)&Td[o + ctile + n][p4 * 4];
#pragma unroll
        for (int m = 0; m < 4; ++m)
#pragma unroll
          for (int n = 0; n < 4; ++n)
            acc[m][n] += a[m].x * b[n].x + a[m].y * b[n].y + a[m].z * b[n].z + a[m].w * b[n].w;
      }
#pragma unroll
      for (int m = 0; m < 4; ++m)
#pragma unroll
        for (int n = 0; n < 4; ++n) X[rtile + m][o + ctile + n] -= acc[m][n];
      __syncthreads();
    }
    // inner solve: X[:, o..o+31] = RHS * U_kk^T — branch-free GEMM vs Uin
    if (tid < NB) {
      int r = tid;
      float4 xo4[8];
#pragma unroll
      for (int p4 = 0; p4 < 8; ++p4) xo4[p4] = *(const float4*)&X[r][o + p4 * 4];
      float xn[NBB];
#pragma unroll
      for (int c = 0; c < NBB; ++c) {
        float s = 0.0f;
#pragma unroll
        for (int p4 = 0; p4 < 8; ++p4) {
          float4 u4 = *(const float4*)&Uin[jb][c][p4 * 4];
          s += xo4[p4].x * u4.x + xo4[p4].y * u4.y + xo4[p4].z * u4.z + xo4[p4].w * u4.w;
        }
        xn[c] = s;
      }
#pragma unroll
      for (int c4 = 0; c4 < 8; ++c4) {
        float4 w; w.x = xn[c4 * 4]; w.y = xn[c4 * 4 + 1];
        w.z = xn[c4 * 4 + 2]; w.w = xn[c4 * 4 + 3];
        *(float4*)&X[r][o + c4 * 4] = w;
      }
    }
    __syncthreads();
  }
  int r = tid >> 1, hf = tid & 1;
  unsigned short* ph = PH + (size_t)i * TILE_ELEMS + (size_t)r * NB + hf * 64;
  unsigned short* pl = PL + (size_t)i * TILE_ELEMS + (size_t)r * NB + hf * 64;
#pragma unroll 1
  for (int ch = 0; ch < 8; ++ch) {
    unsigned short hb[8], lb[8];
#pragma unroll
    for (int e = 0; e < 8; ++e) {
      float v = X[r][hf * 64 + ch * 8 + e];
      unsigned short h = f2bf(v);
      hb[e] = h;
      lb[e] = f2bf(v - bf2f(h));
    }
    *reinterpret_cast<uint4*>(&ph[ch * 8]) = *reinterpret_cast<const uint4*>(hb);
    *reinterpret_cast<uint4*>(&pl[ch * 8]) = *reinterpret_cast<const uint4*>(lb);
  }
}

// ---------------------------------------------------------------------------
// syrk (fused): tile(i,j) -= P_i P_j^T via split-bf16 MFMA (r12-proven).
// WG(0,0) (i=j=k+1, not corner) keeps its update in registers, loads the
// tile into LDS (overlay, 67.6KB — 2 WG/CU), subtracts, runs factor_lds
// (emitting Uinv for step k+1), stores the factored lower triangle.
// ---------------------------------------------------------------------------
__global__ __launch_bounds__(256) void syrk(const unsigned short* __restrict__ PH,
                                            const unsigned short* __restrict__ PL,
                                            float* __restrict__ W,
                                            float* __restrict__ Uinv, int k) {
  int i = k + 1 + blockIdx.x, j = k + 1 + blockIdx.y;
  if (i < j) return;
  __shared__ __align__(16) unsigned char SMEM[SM_SIZE];
  unsigned short (*Ah)[40] = (unsigned short (*)[40])(SMEM);
  unsigned short (*Al)[40] = (unsigned short (*)[40])(SMEM + 10240);
  unsigned short (*Bh)[40] = (unsigned short (*)[40])(SMEM + 20480);
  unsigned short (*Bl)[40] = (unsigned short (*)[40])(SMEM + 30720);
  const unsigned short* Ahg = PH + (size_t)i * TILE_ELEMS;
  const unsigned short* Alg = PL + (size_t)i * TILE_ELEMS;
  const unsigned short* Bhg = PH + (size_t)j * TILE_ELEMS;
  const unsigned short* Blg = PL + (size_t)j * TILE_ELEMS;
  float* C = W + tile_off(i, j);
  int tid = threadIdx.x, lane = tid & 63, wid = tid >> 6;
  int wr = wid >> 1, wc = wid & 1, lm = lane & 15, lk = lane >> 4;
  f32x4 acc[4][4];
#pragma unroll
  for (int m = 0; m < 4; ++m)
#pragma unroll
    for (int n = 0; n < 4; ++n) acc[m][n] = (f32x4)0.0f;
  int r = tid >> 1, hf = tid & 1;
#pragma unroll 1
  for (int kb = 0; kb < 4; ++kb) {
    int kbase = kb * 32;
    if (kb) __syncthreads();
#pragma unroll
    for (int c = 0; c < 2; ++c) {
      int lc = (hf * 2 + c) * 8;
      int kc = kbase + lc;
      *reinterpret_cast<uint4*>(&Ah[r][lc]) = *reinterpret_cast<const uint4*>(&Ahg[(size_t)r * NB + kc]);
      *reinterpret_cast<uint4*>(&Al[r][lc]) = *reinterpret_cast<const uint4*>(&Alg[(size_t)r * NB + kc]);
      *reinterpret_cast<uint4*>(&Bh[r][lc]) = *reinterpret_cast<const uint4*>(&Bhg[(size_t)r * NB + kc]);
      *reinterpret_cast<uint4*>(&Bl[r][lc]) = *reinterpret_cast<const uint4*>(&Blg[(size_t)r * NB + kc]);
    }
    __syncthreads();
    bf16x8 ah[4], al[4], bh[4], bl[4];
#pragma unroll
    for (int mt = 0; mt < 4; ++mt) {
      int row = wr * 64 + mt * 16 + lm;
      ah[mt] = *reinterpret_cast<const bf16x8*>(&Ah[row][lk * 8]);
      al[mt] = *reinterpret_cast<const bf16x8*>(&Al[row][lk * 8]);
    }
#pragma unroll
    for (int nt = 0; nt < 4; ++nt) {
      int col = wc * 64 + nt * 16 + lm;
      bh[nt] = *reinterpret_cast<const bf16x8*>(&Bh[col][lk * 8]);
      bl[nt] = *reinterpret_cast<const bf16x8*>(&Bl[col][lk * 8]);
    }
#pragma unroll
    for (int mt = 0; mt < 4; ++mt)
#pragma unroll
      for (int nt = 0; nt < 4; ++nt) {
        acc[mt][nt] = __builtin_amdgcn_mfma_f32_16x16x32_bf16(ah[mt], bh[nt], acc[mt][nt], 0, 0, 0);
        acc[mt][nt] = __builtin_amdgcn_mfma_f32_16x16x32_bf16(al[mt], bh[nt], acc[mt][nt], 0, 0, 0);
        acc[mt][nt] = __builtin_amdgcn_mfma_f32_16x16x32_bf16(ah[mt], bl[nt], acc[mt][nt], 0, 0, 0);
      }
  }
  bool dofac = (blockIdx.x == 0 && blockIdx.y == 0 && i < NBLK - 1);
  if (!dofac) {
#pragma unroll
    for (int mt = 0; mt < 4; ++mt)
#pragma unroll
      for (int nt = 0; nt < 4; ++nt) {
#pragma unroll
        for (int q = 0; q < 4; ++q) {
          int rr = wr * 64 + mt * 16 + lk * 4 + q;
          int cc = wc * 64 + nt * 16 + lm;
          C[rr * NB + cc] -= acc[mt][nt][q];
        }
      }
  } else {
    __syncthreads();   // staging LDS reads done; SMEM reusable as T
    float (*T)[NBP] = (float (*)[NBP])SMEM;
    for (int idx = tid; idx < TILE_ELEMS / 4; idx += 256) {
      float4 v = ((const float4*)C)[idx];
      int rr = idx >> 5, cc = (idx & 31) * 4;
      *(float4*)&T[rr][cc] = v;
    }
    __syncthreads();
#pragma unroll
    for (int mt = 0; mt < 4; ++mt)
#pragma unroll
      for (int nt = 0; nt < 4; ++nt) {
#pragma unroll
        for (int q = 0; q < 4; ++q) {
          int rr = wr * 64 + mt * 16 + lk * 4 + q;
          int cc = wc * 64 + nt * 16 + lm;
          T[rr][cc] -= acc[mt][nt][q];
        }
      }
    __syncthreads();
    factor_lds(T, Uinv, tid);
    for (int idx = tid; idx < TILE_ELEMS; idx += 256) {
      int rr = idx >> 7, cc = idx & 127;
      if (cc <= rr) C[idx] = T[rr][cc];
    }
  }
}

// ---------------------------------------------------------------------------
// finalize: -lml from corner trace and diag of L. (r11/r12-proven verbatim)
// ---------------------------------------------------------------------------
__global__ __launch_bounds__(256) void finalize(const float* __restrict__ W,
                                                const int* __restrict__ bsp,
                                                const int* __restrict__ tmaxp,
                                                float* __restrict__ out) {
  __shared__ float rl[4], rq[4];
  int tid = threadIdx.x;
  float lsum = 0.0f;
  for (int d = tid; d < Nn; d += 256) {
    int db = d >> 7, dl = d & 127;
    lsum += logf(W[tile_off(db, db) + (size_t)dl * NB + dl]);
  }
  float qsum = 0.0f;
  if (tid < BSc) qsum = W[tile_off(NBLK - 1, NBLK - 1) + (size_t)tid * NB + tid];
  for (int o = 32; o > 0; o >>= 1) {
    lsum += __shfl_down(lsum, o, 64);
    qsum += __shfl_down(qsum, o, 64);
  }
  int lane = tid & 63, wid = tid >> 6;
  if (lane == 0) { rl[wid] = lsum; rq[wid] = qsum; }
  __syncthreads();
  if (tid == 0) {
    float Lt = rl[0] + rl[1] + rl[2] + rl[3];
    float Qt = rq[0] + rq[1] + rq[2] + rq[3];
    float bsf = (float)bsp[0];
    float tmaxf = (float)tmaxp[0];
    out[0] = -Qt / (2.0f * bsf) + Lt + 0.5f * tmaxf * logf(6.283185307179586f);
  }
}

extern "C" void kernel_launch(void* const* d_in, const int* in_sizes, int n_in,
                              void* d_out, int out_size, void* d_ws, size_t ws_size,
                              hipStream_t stream) {
  const float* Y   = (const float*)d_in[0];
  const float* mu  = (const float*)d_in[1];
  const float* Kp  = (const float*)d_in[2];
  const float* Sg  = (const float*)d_in[3];
  const int*   bsp = (const int*)d_in[4];
  const int*   tmp_= (const int*)d_in[5];
  float* W = (float*)d_ws;                                                  // 36.8 MB
  unsigned short* PH = (unsigned short*)(W + (size_t)NTILES * TILE_ELEMS);  // 33 tiles bf16 hi
  unsigned short* PL = PH + (size_t)NBLK * TILE_ELEMS;                      // 33 tiles bf16 lo
  float* Uinv = (float*)(PL + (size_t)NBLK * TILE_ELEMS);                   // 4x32x32 fp32
  float* out = (float*)d_out;

  prep<<<NTILES, 256, 0, stream>>>(Y, mu, Kp, Sg, W);
  potf2<<<1, 256, 0, stream>>>(W, Uinv, 0);   // one-shot: factor tile(0,0)

  for (int k = 0; k < NK; ++k) {
    int T = NBLK - (k + 1);
    trsm<<<T, 256, 0, stream>>>(W, Uinv, PH, PL, k);
    dim3 g(T, T);
    syrk<<<g, 256, 0, stream>>>(PH, PL, W, Uinv, k);  // WG(0,0) factors tile(k+1,k+1)
  }
  finalize<<<1, 256, 0, stream>>>(W, bsp, tmp_, out);
}

// Round 14
// 3693.162 us; speedup vs baseline: 1.9760x; 1.9760x over previous
//
#include <hip/hip_runtime.h>
#include <math.h>

// Fixed instance constants.
#define Nn 4096          // n = m * tmax
#define BSc 32           // batch size (border rows)
#define NB 128           // block size
#define NBP 132          // padded LDS row stride (16B-aligned rows)
#define NBB 32           // sub-block for recursive factorization
#define NBLK 33          // block-rows: 32 full + 1 border (32 rows)
#define NK 32            // factorization steps
#define TILE_ELEMS (NB * NB)
#define NTILES 561       // NBLK*(NBLK+1)/2 lower tiles

// Fused-syrk LDS overlay: union of {4x bf16 staging tiles = 40960B} and
// {T[128][132] fp32 = 67584B + dinv[32] = 128B}.
#define SM_DINV 67584
#define SM_SIZE 67712

typedef float f32x4 __attribute__((ext_vector_type(4)));
typedef short bf16x8 __attribute__((ext_vector_type(8)));

// Packed lower-block-triangular storage: tile(i,j), 0<=j<=i<=32.
__device__ __forceinline__ size_t tile_off(int i, int j) {
  return ((size_t)(j * NBLK - (j * (j - 1)) / 2 + (i - j))) * TILE_ELEMS;
}

// fp32 -> bf16 (round-to-nearest-even).
__device__ __forceinline__ unsigned short f2bf(float f) {
  union { float f; unsigned int u; } v; v.f = f;
  unsigned int r = v.u + 0x7fffu + ((v.u >> 16) & 1u);
  return (unsigned short)(r >> 16);
}
__device__ __forceinline__ float bf2f(unsigned short b) {
  union { unsigned int u; float f; } v; v.u = ((unsigned int)b) << 16;
  return v.f;
}

// ---------------------------------------------------------------------------
// prep: fill stored tiles from the virtual bordered matrix. (r2..r12-proven)
// ---------------------------------------------------------------------------
__global__ __launch_bounds__(256) void prep(const float* __restrict__ Y,
                                            const float* __restrict__ mu,
                                            const float* __restrict__ Kp,
                                            const float* __restrict__ Sg,
                                            float* __restrict__ W) {
  int bid = blockIdx.x;
  int j = 0;
  while (j + 1 < NBLK) {
    int nxt = (j + 1) * NBLK - ((j + 1) * j) / 2;
    if (bid < nxt) break;
    ++j;
  }
  int start = j * NBLK - (j * (j - 1)) / 2;
  int i = j + (bid - start);
  float* T = W + tile_off(i, j);
  int tid = threadIdx.x;
  for (int idx = tid; idx < TILE_ELEMS; idx += 256) {
    int li = idx >> 7, lj = idx & 127;
    int gr = i * NB + li, gc = j * NB + lj;
    float v = 0.0f;
    if (gr < Nn) {
      v = Kp[(size_t)gr * Nn + gc];
      if (gr == gc) v += Sg[(size_t)gr * Nn + gr];
    } else {
      int b = gr - Nn;
      if (b < BSc && gc < Nn) v = mu[gc] - Y[(size_t)b * Nn + gc];
    }
    T[idx] = v;
  }
}

// ---------------------------------------------------------------------------
// factor_lds: r11/r12-proven potf2 phases operating on T (LDS) in place.
// A: Crout register Cholesky per 32-block; B: row-parallel solve (float4 IO);
// C: float4 trailing rank-32 update. Caller barriers before/after.
// ---------------------------------------------------------------------------
__device__ __forceinline__ void factor_lds(float (*T)[NBP], float* dinv_sh,
                                           int tid) {
  int lane = tid & 63, wid = tid >> 6;
#pragma unroll 1
  for (int kb = 0; kb < 4; ++kb) {
    int o = kb * NBB;
    // --- A: 32x32 diagonal block, Crout register factorization (proven) ---
    if (wid == 0) {
      int ii = lane & 31;
      float cc[NBB];
#pragma unroll
      for (int p = 0; p < NBB; ++p) cc[p] = T[o + ii][o + p];
#pragma unroll
      for (int j = 0; j < NBB; ++j) {
        float s = cc[j];
#pragma unroll
        for (int p = 0; p < NBB; ++p) {
          if (p < j) s -= cc[p] * __shfl(cc[p], j, 64);
        }
        float sj = __shfl(s, j, 64);
        float d = sqrtf(sj);
        if (ii == j) cc[j] = d;
        else if (ii > j) cc[j] = s / d;
      }
      if (lane < 32) {
#pragma unroll
        for (int p = 0; p < NBB; ++p) {
          if (p <= ii) T[o + ii][o + p] = cc[p];
        }
      }
    }
    __syncthreads();
    if (tid < NBB) dinv_sh[tid] = 1.0f / T[o + tid][o + tid];
    __syncthreads();
    int R = NB - o - NBB;   // trailing rows: 96, 64, 32, 0
    if (R > 0) {
      // --- B: solve trailing rows against the factored triangle ---
      if (tid < R) {
        int r = o + NBB + tid;
        float x[NBB];
#pragma unroll
        for (int p4 = 0; p4 < 8; ++p4) {
          float4 v = *(const float4*)&T[r][o + p4 * 4];
          x[p4 * 4] = v.x; x[p4 * 4 + 1] = v.y; x[p4 * 4 + 2] = v.z; x[p4 * 4 + 3] = v.w;
        }
#pragma unroll
        for (int j = 0; j < NBB; ++j) {
          float s = x[j];
#pragma unroll
          for (int p = 0; p < NBB; ++p) {
            if (p < j) s -= x[p] * T[o + j][o + p];
          }
          x[j] = s * dinv_sh[j];
        }
#pragma unroll
        for (int c4 = 0; c4 < 8; ++c4) {
          float4 w; w.x = x[c4 * 4]; w.y = x[c4 * 4 + 1]; w.z = x[c4 * 4 + 2]; w.w = x[c4 * 4 + 3];
          *(float4*)&T[r][o + c4 * 4] = w;
        }
      }
      __syncthreads();
      // --- C: trailing rank-32 update, lower 4x4 tiles, float4 (proven) ---
      int TL = R >> 2;
      int ntile = TL * (TL + 1) / 2;
#pragma unroll 1
      for (int t = tid; t < ntile; t += 256) {
        int ti = (int)((sqrtf(8.0f * t + 1.0f) - 1.0f) * 0.5f);
        while ((ti + 1) * (ti + 2) / 2 <= t) ++ti;
        while (ti * (ti + 1) / 2 > t) --ti;
        int tj = t - ti * (ti + 1) / 2;
        int tr = o + NBB + ti * 4, tc = o + NBB + tj * 4;
        float acc[4][4];
#pragma unroll
        for (int m = 0; m < 4; ++m)
#pragma unroll
          for (int n = 0; n < 4; ++n) acc[m][n] = 0.0f;
#pragma unroll
        for (int p4 = 0; p4 < 8; ++p4) {
          float4 a[4], b[4];
#pragma unroll
          for (int m = 0; m < 4; ++m) a[m] = *(const float4*)&T[tr + m][o + p4 * 4];
#pragma unroll
          for (int n = 0; n < 4; ++n) b[n] = *(const float4*)&T[tc + n][o + p4 * 4];
#pragma unroll
          for (int m = 0; m < 4; ++m)
#pragma unroll
            for (int n = 0; n < 4; ++n)
              acc[m][n] += a[m].x * b[n].x + a[m].y * b[n].y + a[m].z * b[n].z + a[m].w * b[n].w;
        }
#pragma unroll
        for (int m = 0; m < 4; ++m)
#pragma unroll
          for (int n = 0; n < 4; ++n) T[tr + m][tc + n] -= acc[m][n];
      }
    }
    __syncthreads();
  }
}

// ---------------------------------------------------------------------------
// potf2: one-shot factor of tile(0,0) (r11/r12 structure, shared factor body).
// ---------------------------------------------------------------------------
__global__ __launch_bounds__(256) void potf2(float* __restrict__ W, int k) {
  __shared__ __align__(16) unsigned char SMEM[SM_SIZE];
  float (*T)[NBP] = (float (*)[NBP])SMEM;
  float* dinv_sh = (float*)(SMEM + SM_DINV);
  float* G = W + tile_off(k, k);
  int tid = threadIdx.x;
  for (int idx = tid; idx < TILE_ELEMS / 4; idx += 256) {
    float4 v = ((const float4*)G)[idx];
    int r = idx >> 5, c = (idx & 31) * 4;
    *(float4*)&T[r][c] = v;
  }
  __syncthreads();
  factor_lds(T, dinv_sh, tid);
  for (int idx = tid; idx < TILE_ELEMS; idx += 256) {
    int i = idx >> 7, j = idx & 127;
    if (j <= i) G[idx] = T[i][j];
  }
}

// ---------------------------------------------------------------------------
// trsm: tile(i,k) <- tile(i,k) * L_kk^{-T}; split-bf16 panel epilogue.
// (r11/r12-proven verbatim)
// ---------------------------------------------------------------------------
__global__ __launch_bounds__(256) void trsm(float* __restrict__ W,
                                            unsigned short* __restrict__ PH,
                                            unsigned short* __restrict__ PL,
                                            int k) {
  __shared__ float Td[NB][NBP];
  __shared__ float X[NB][NBP];
  __shared__ float dinv_sh[NB];
  int tid = threadIdx.x;
  int i = k + 1 + blockIdx.x;
  int rows = (i == NBLK - 1) ? BSc : NB;
  const float* Gd = W + tile_off(k, k);
  const float* Gx = W + tile_off(i, k);
  for (int idx = tid; idx < TILE_ELEMS / 4; idx += 256) {
    float4 v = ((const float4*)Gd)[idx];
    float4 u = ((const float4*)Gx)[idx];
    int r = idx >> 5, c = (idx & 31) * 4;
    *(float4*)&Td[r][c] = v;
    if (r >= rows) { u.x = 0.0f; u.y = 0.0f; u.z = 0.0f; u.w = 0.0f; }
    *(float4*)&X[r][c] = u;
  }
  __syncthreads();
  if (tid < NB) dinv_sh[tid] = 1.0f / Td[tid][tid];
  __syncthreads();
  int rtile = (tid >> 3) * 4;
  int ctile = (tid & 7) * 4;
#pragma unroll 1
  for (int jb = 0; jb < 4; ++jb) {
    int o = jb * NBB;
    if (jb > 0) {
      float acc[4][4];
#pragma unroll
      for (int m = 0; m < 4; ++m)
#pragma unroll
        for (int n = 0; n < 4; ++n) acc[m][n] = 0.0f;
#pragma unroll 1
      for (int p4 = 0; p4 < (o >> 2); ++p4) {
        float4 a[4], b[4];
#pragma unroll
        for (int m = 0; m < 4; ++m) a[m] = *(const float4*)&X[rtile + m][p4 * 4];
#pragma unroll
        for (int n = 0; n < 4; ++n) b[n] = *(const float4*)&Td[o + ctile + n][p4 * 4];
#pragma unroll
        for (int m = 0; m < 4; ++m)
#pragma unroll
          for (int n = 0; n < 4; ++n)
            acc[m][n] += a[m].x * b[n].x + a[m].y * b[n].y + a[m].z * b[n].z + a[m].w * b[n].w;
      }
#pragma unroll
      for (int m = 0; m < 4; ++m)
#pragma unroll
        for (int n = 0; n < 4; ++n) X[rtile + m][o + ctile + n] -= acc[m][n];
      __syncthreads();
    }
    if (tid < NB) {
      int r = tid;
      float x[NBB];
#pragma unroll
      for (int p4 = 0; p4 < 8; ++p4) {
        float4 v = *(const float4*)&X[r][o + p4 * 4];
        x[p4 * 4] = v.x; x[p4 * 4 + 1] = v.y; x[p4 * 4 + 2] = v.z; x[p4 * 4 + 3] = v.w;
      }
#pragma unroll
      for (int j = 0; j < NBB; ++j) {
        float s = x[j];
#pragma unroll
        for (int p = 0; p < NBB; ++p) {
          if (p < j) s -= x[p] * Td[o + j][o + p];
        }
        x[j] = s * dinv_sh[o + j];
      }
#pragma unroll
      for (int c4 = 0; c4 < 8; ++c4) {
        float4 w; w.x = x[c4 * 4]; w.y = x[c4 * 4 + 1]; w.z = x[c4 * 4 + 2]; w.w = x[c4 * 4 + 3];
        *(float4*)&X[r][o + c4 * 4] = w;
      }
    }
    __syncthreads();
  }
  int r = tid >> 1, hf = tid & 1;
  unsigned short* ph = PH + (size_t)i * TILE_ELEMS + (size_t)r * NB + hf * 64;
  unsigned short* pl = PL + (size_t)i * TILE_ELEMS + (size_t)r * NB + hf * 64;
#pragma unroll 1
  for (int ch = 0; ch < 8; ++ch) {
    unsigned short hb[8], lb[8];
#pragma unroll
    for (int e = 0; e < 8; ++e) {
      float v = X[r][hf * 64 + ch * 8 + e];
      unsigned short h = f2bf(v);
      hb[e] = h;
      lb[e] = f2bf(v - bf2f(h));
    }
    *reinterpret_cast<uint4*>(&ph[ch * 8]) = *reinterpret_cast<const uint4*>(hb);
    *reinterpret_cast<uint4*>(&pl[ch * 8]) = *reinterpret_cast<const uint4*>(lb);
  }
}

// ---------------------------------------------------------------------------
// syrk (fused): tile(i,j) -= P_i P_j^T via split-bf16 MFMA (r4/r11-proven).
// WG(0,0) (i=j=k+1, not corner) keeps its update in registers, loads the
// tile into LDS (overlay, 67.7KB — syrk stays at 2 WG/CU), subtracts, runs
// factor_lds, and stores the factored lower triangle. The factor runs
// concurrently with all other syrk WGs instead of as a serial dispatch.
// ---------------------------------------------------------------------------
__global__ __launch_bounds__(256) void syrk(const unsigned short* __restrict__ PH,
                                            const unsigned short* __restrict__ PL,
                                            float* __restrict__ W, int k) {
  int i = k + 1 + blockIdx.x, j = k + 1 + blockIdx.y;
  if (i < j) return;
  __shared__ __align__(16) unsigned char SMEM[SM_SIZE];
  unsigned short (*Ah)[40] = (unsigned short (*)[40])(SMEM);
  unsigned short (*Al)[40] = (unsigned short (*)[40])(SMEM + 10240);
  unsigned short (*Bh)[40] = (unsigned short (*)[40])(SMEM + 20480);
  unsigned short (*Bl)[40] = (unsigned short (*)[40])(SMEM + 30720);
  const unsigned short* Ahg = PH + (size_t)i * TILE_ELEMS;
  const unsigned short* Alg = PL + (size_t)i * TILE_ELEMS;
  const unsigned short* Bhg = PH + (size_t)j * TILE_ELEMS;
  const unsigned short* Blg = PL + (size_t)j * TILE_ELEMS;
  float* C = W + tile_off(i, j);
  int tid = threadIdx.x, lane = tid & 63, wid = tid >> 6;
  int wr = wid >> 1, wc = wid & 1, lm = lane & 15, lk = lane >> 4;
  f32x4 acc[4][4];
#pragma unroll
  for (int m = 0; m < 4; ++m)
#pragma unroll
    for (int n = 0; n < 4; ++n) acc[m][n] = (f32x4)0.0f;
  int r = tid >> 1, hf = tid & 1;
#pragma unroll 1
  for (int kb = 0; kb < 4; ++kb) {
    int kbase = kb * 32;
    if (kb) __syncthreads();
#pragma unroll
    for (int c = 0; c < 2; ++c) {
      int lc = (hf * 2 + c) * 8;
      int kc = kbase + lc;
      *reinterpret_cast<uint4*>(&Ah[r][lc]) = *reinterpret_cast<const uint4*>(&Ahg[(size_t)r * NB + kc]);
      *reinterpret_cast<uint4*>(&Al[r][lc]) = *reinterpret_cast<const uint4*>(&Alg[(size_t)r * NB + kc]);
      *reinterpret_cast<uint4*>(&Bh[r][lc]) = *reinterpret_cast<const uint4*>(&Bhg[(size_t)r * NB + kc]);
      *reinterpret_cast<uint4*>(&Bl[r][lc]) = *reinterpret_cast<const uint4*>(&Blg[(size_t)r * NB + kc]);
    }
    __syncthreads();
    bf16x8 ah[4], al[4], bh[4], bl[4];
#pragma unroll
    for (int mt = 0; mt < 4; ++mt) {
      int row = wr * 64 + mt * 16 + lm;
      ah[mt] = *reinterpret_cast<const bf16x8*>(&Ah[row][lk * 8]);
      al[mt] = *reinterpret_cast<const bf16x8*>(&Al[row][lk * 8]);
    }
#pragma unroll
    for (int nt = 0; nt < 4; ++nt) {
      int col = wc * 64 + nt * 16 + lm;
      bh[nt] = *reinterpret_cast<const bf16x8*>(&Bh[col][lk * 8]);
      bl[nt] = *reinterpret_cast<const bf16x8*>(&Bl[col][lk * 8]);
    }
#pragma unroll
    for (int mt = 0; mt < 4; ++mt)
#pragma unroll
      for (int nt = 0; nt < 4; ++nt) {
        acc[mt][nt] = __builtin_amdgcn_mfma_f32_16x16x32_bf16(ah[mt], bh[nt], acc[mt][nt], 0, 0, 0);
        acc[mt][nt] = __builtin_amdgcn_mfma_f32_16x16x32_bf16(al[mt], bh[nt], acc[mt][nt], 0, 0, 0);
        acc[mt][nt] = __builtin_amdgcn_mfma_f32_16x16x32_bf16(ah[mt], bl[nt], acc[mt][nt], 0, 0, 0);
      }
  }
  bool dofac = (blockIdx.x == 0 && blockIdx.y == 0 && i < NBLK - 1);
  if (!dofac) {
#pragma unroll
    for (int mt = 0; mt < 4; ++mt)
#pragma unroll
      for (int nt = 0; nt < 4; ++nt) {
#pragma unroll
        for (int q = 0; q < 4; ++q) {
          int rr = wr * 64 + mt * 16 + lk * 4 + q;
          int cc = wc * 64 + nt * 16 + lm;
          C[rr * NB + cc] -= acc[mt][nt][q];
        }
      }
  } else {
    __syncthreads();   // staging LDS reads done; SMEM reusable as T
    float (*T)[NBP] = (float (*)[NBP])SMEM;
    float* dinv_sh = (float*)(SMEM + SM_DINV);
    for (int idx = tid; idx < TILE_ELEMS / 4; idx += 256) {
      float4 v = ((const float4*)C)[idx];
      int rr = idx >> 5, cc = (idx & 31) * 4;
      *(float4*)&T[rr][cc] = v;
    }
    __syncthreads();
#pragma unroll
    for (int mt = 0; mt < 4; ++mt)
#pragma unroll
      for (int nt = 0; nt < 4; ++nt) {
#pragma unroll
        for (int q = 0; q < 4; ++q) {
          int rr = wr * 64 + mt * 16 + lk * 4 + q;
          int cc = wc * 64 + nt * 16 + lm;
          T[rr][cc] -= acc[mt][nt][q];
        }
      }
    __syncthreads();
    factor_lds(T, dinv_sh, tid);
    for (int idx = tid; idx < TILE_ELEMS; idx += 256) {
      int rr = idx >> 7, cc = idx & 127;
      if (cc <= rr) C[idx] = T[rr][cc];
    }
  }
}

// ---------------------------------------------------------------------------
// finalize: -lml from corner trace and diag of L. (r11/r12-proven verbatim)
// ---------------------------------------------------------------------------
__global__ __launch_bounds__(256) void finalize(const float* __restrict__ W,
                                                const int* __restrict__ bsp,
                                                const int* __restrict__ tmaxp,
                                                float* __restrict__ out) {
  __shared__ float rl[4], rq[4];
  int tid = threadIdx.x;
  float lsum = 0.0f;
  for (int d = tid; d < Nn; d += 256) {
    int db = d >> 7, dl = d & 127;
    lsum += logf(W[tile_off(db, db) + (size_t)dl * NB + dl]);
  }
  float qsum = 0.0f;
  if (tid < BSc) qsum = W[tile_off(NBLK - 1, NBLK - 1) + (size_t)tid * NB + tid];
  for (int o = 32; o > 0; o >>= 1) {
    lsum += __shfl_down(lsum, o, 64);
    qsum += __shfl_down(qsum, o, 64);
  }
  int lane = tid & 63, wid = tid >> 6;
  if (lane == 0) { rl[wid] = lsum; rq[wid] = qsum; }
  __syncthreads();
  if (tid == 0) {
    float Lt = rl[0] + rl[1] + rl[2] + rl[3];
    float Qt = rq[0] + rq[1] + rq[2] + rq[3];
    float bsf = (float)bsp[0];
    float tmaxf = (float)tmaxp[0];
    out[0] = -Qt / (2.0f * bsf) + Lt + 0.5f * tmaxf * logf(6.283185307179586f);
  }
}

extern "C" void kernel_launch(void* const* d_in, const int* in_sizes, int n_in,
                              void* d_out, int out_size, void* d_ws, size_t ws_size,
                              hipStream_t stream) {
  const float* Y   = (const float*)d_in[0];
  const float* mu  = (const float*)d_in[1];
  const float* Kp  = (const float*)d_in[2];
  const float* Sg  = (const float*)d_in[3];
  const int*   bsp = (const int*)d_in[4];
  const int*   tmp_= (const int*)d_in[5];
  float* W = (float*)d_ws;                                                  // 36.8 MB
  unsigned short* PH = (unsigned short*)(W + (size_t)NTILES * TILE_ELEMS);  // 33 tiles bf16 hi
  unsigned short* PL = PH + (size_t)NBLK * TILE_ELEMS;                      // 33 tiles bf16 lo
  float* out = (float*)d_out;

  prep<<<NTILES, 256, 0, stream>>>(Y, mu, Kp, Sg, W);
  potf2<<<1, 256, 0, stream>>>(W, 0);   // one-shot: factor tile(0,0)

  for (int k = 0; k < NK; ++k) {
    int T = NBLK - (k + 1);
    trsm<<<T, 256, 0, stream>>>(W, PH, PL, k);
    dim3 g(T, T);
    syrk<<<g, 256, 0, stream>>>(PH, PL, W, k);   // WG(0,0) also factors tile(k+1,k+1)
  }
  finalize<<<1, 256, 0, stream>>>(W, bsp, tmp_, out);
}

// Round 15
// 3670.245 us; speedup vs baseline: 1.9883x; 1.0062x over previous
//
#include <hip/hip_runtime.h>
#include <math.h>

// Fixed instance constants.
#define Nn 4096          // n = m * tmax
#define BSc 32           // batch size (border rows)
#define NB 128           // block size
#define NBP 132          // padded LDS row stride (16B-aligned rows)
#define NBB 32           // sub-block for recursive factorization
#define NBLK 33          // block-rows: 32 full + 1 border (32 rows)
#define NK 32            // factorization steps
#define TILE_ELEMS (NB * NB)
#define NTILES 561       // NBLK*(NBLK+1)/2 lower tiles

// Fused-syrk LDS overlay: union of {4x bf16 staging tiles = 40960B} and
// {T[128][132] fp32 = 67584B + dinv[32] = 128B}.
#define SM_DINV 67584
#define SM_SIZE 67712

typedef float f32x4 __attribute__((ext_vector_type(4)));
typedef short bf16x8 __attribute__((ext_vector_type(8)));

// Packed lower-block-triangular storage: tile(i,j), 0<=j<=i<=32.
__device__ __forceinline__ size_t tile_off(int i, int j) {
  return ((size_t)(j * NBLK - (j * (j - 1)) / 2 + (i - j))) * TILE_ELEMS;
}

// fp32 -> bf16 (round-to-nearest-even).
__device__ __forceinline__ unsigned short f2bf(float f) {
  union { float f; unsigned int u; } v; v.f = f;
  unsigned int r = v.u + 0x7fffu + ((v.u >> 16) & 1u);
  return (unsigned short)(r >> 16);
}
__device__ __forceinline__ float bf2f(unsigned short b) {
  union { unsigned int u; float f; } v; v.u = ((unsigned int)b) << 16;
  return v.f;
}

// ---------------------------------------------------------------------------
// prep: fill stored tiles from the virtual bordered matrix. (r2..r14-proven)
// ---------------------------------------------------------------------------
__global__ __launch_bounds__(256) void prep(const float* __restrict__ Y,
                                            const float* __restrict__ mu,
                                            const float* __restrict__ Kp,
                                            const float* __restrict__ Sg,
                                            float* __restrict__ W) {
  int bid = blockIdx.x;
  int j = 0;
  while (j + 1 < NBLK) {
    int nxt = (j + 1) * NBLK - ((j + 1) * j) / 2;
    if (bid < nxt) break;
    ++j;
  }
  int start = j * NBLK - (j * (j - 1)) / 2;
  int i = j + (bid - start);
  float* T = W + tile_off(i, j);
  int tid = threadIdx.x;
  for (int idx = tid; idx < TILE_ELEMS; idx += 256) {
    int li = idx >> 7, lj = idx & 127;
    int gr = i * NB + li, gc = j * NB + lj;
    float v = 0.0f;
    if (gr < Nn) {
      v = Kp[(size_t)gr * Nn + gc];
      if (gr == gc) v += Sg[(size_t)gr * Nn + gr];
    } else {
      int b = gr - Nn;
      if (b < BSc && gc < Nn) v = mu[gc] - Y[(size_t)b * Nn + gc];
    }
    T[idx] = v;
  }
}

// ---------------------------------------------------------------------------
// factor_lds: r11/r12-proven potf2 phases operating on T (LDS) in place.
// A: Crout register Cholesky per 32-block; B: row-parallel solve (float4 IO);
// C: float4 trailing rank-32 update. Caller barriers before/after.
// ---------------------------------------------------------------------------
__device__ __forceinline__ void factor_lds(float (*T)[NBP], float* dinv_sh,
                                           int tid) {
  int lane = tid & 63, wid = tid >> 6;
#pragma unroll 1
  for (int kb = 0; kb < 4; ++kb) {
    int o = kb * NBB;
    // --- A: 32x32 diagonal block, Crout register factorization (proven) ---
    if (wid == 0) {
      int ii = lane & 31;
      float cc[NBB];
#pragma unroll
      for (int p = 0; p < NBB; ++p) cc[p] = T[o + ii][o + p];
#pragma unroll
      for (int j = 0; j < NBB; ++j) {
        float s = cc[j];
#pragma unroll
        for (int p = 0; p < NBB; ++p) {
          if (p < j) s -= cc[p] * __shfl(cc[p], j, 64);
        }
        float sj = __shfl(s, j, 64);
        float d = sqrtf(sj);
        if (ii == j) cc[j] = d;
        else if (ii > j) cc[j] = s / d;
      }
      if (lane < 32) {
#pragma unroll
        for (int p = 0; p < NBB; ++p) {
          if (p <= ii) T[o + ii][o + p] = cc[p];
        }
      }
    }
    __syncthreads();
    if (tid < NBB) dinv_sh[tid] = 1.0f / T[o + tid][o + tid];
    __syncthreads();
    int R = NB - o - NBB;   // trailing rows: 96, 64, 32, 0
    if (R > 0) {
      // --- B: solve trailing rows against the factored triangle ---
      if (tid < R) {
        int r = o + NBB + tid;
        float x[NBB];
#pragma unroll
        for (int p4 = 0; p4 < 8; ++p4) {
          float4 v = *(const float4*)&T[r][o + p4 * 4];
          x[p4 * 4] = v.x; x[p4 * 4 + 1] = v.y; x[p4 * 4 + 2] = v.z; x[p4 * 4 + 3] = v.w;
        }
#pragma unroll
        for (int j = 0; j < NBB; ++j) {
          float s = x[j];
#pragma unroll
          for (int p = 0; p < NBB; ++p) {
            if (p < j) s -= x[p] * T[o + j][o + p];
          }
          x[j] = s * dinv_sh[j];
        }
#pragma unroll
        for (int c4 = 0; c4 < 8; ++c4) {
          float4 w; w.x = x[c4 * 4]; w.y = x[c4 * 4 + 1]; w.z = x[c4 * 4 + 2]; w.w = x[c4 * 4 + 3];
          *(float4*)&T[r][o + c4 * 4] = w;
        }
      }
      __syncthreads();
      // --- C: trailing rank-32 update, lower 4x4 tiles, float4 (proven) ---
      int TL = R >> 2;
      int ntile = TL * (TL + 1) / 2;
#pragma unroll 1
      for (int t = tid; t < ntile; t += 256) {
        int ti = (int)((sqrtf(8.0f * t + 1.0f) - 1.0f) * 0.5f);
        while ((ti + 1) * (ti + 2) / 2 <= t) ++ti;
        while (ti * (ti + 1) / 2 > t) --ti;
        int tj = t - ti * (ti + 1) / 2;
        int tr = o + NBB + ti * 4, tc = o + NBB + tj * 4;
        float acc[4][4];
#pragma unroll
        for (int m = 0; m < 4; ++m)
#pragma unroll
          for (int n = 0; n < 4; ++n) acc[m][n] = 0.0f;
#pragma unroll
        for (int p4 = 0; p4 < 8; ++p4) {
          float4 a[4], b[4];
#pragma unroll
          for (int m = 0; m < 4; ++m) a[m] = *(const float4*)&T[tr + m][o + p4 * 4];
#pragma unroll
          for (int n = 0; n < 4; ++n) b[n] = *(const float4*)&T[tc + n][o + p4 * 4];
#pragma unroll
          for (int m = 0; m < 4; ++m)
#pragma unroll
            for (int n = 0; n < 4; ++n)
              acc[m][n] += a[m].x * b[n].x + a[m].y * b[n].y + a[m].z * b[n].z + a[m].w * b[n].w;
        }
#pragma unroll
        for (int m = 0; m < 4; ++m)
#pragma unroll
          for (int n = 0; n < 4; ++n) T[tr + m][tc + n] -= acc[m][n];
      }
    }
    __syncthreads();
  }
}

// ---------------------------------------------------------------------------
// potf2: one-shot factor of tile(0,0) (r11/r12 structure, shared factor body).
// ---------------------------------------------------------------------------
__global__ __launch_bounds__(256) void potf2(float* __restrict__ W, int k) {
  __shared__ __align__(16) unsigned char SMEM[SM_SIZE];
  float (*T)[NBP] = (float (*)[NBP])SMEM;
  float* dinv_sh = (float*)(SMEM + SM_DINV);
  float* G = W + tile_off(k, k);
  int tid = threadIdx.x;
  for (int idx = tid; idx < TILE_ELEMS / 4; idx += 256) {
    float4 v = ((const float4*)G)[idx];
    int r = idx >> 5, c = (idx & 31) * 4;
    *(float4*)&T[r][c] = v;
  }
  __syncthreads();
  factor_lds(T, dinv_sh, tid);
  for (int idx = tid; idx < TILE_ELEMS; idx += 256) {
    int i = idx >> 7, j = idx & 127;
    if (j <= i) G[idx] = T[i][j];
  }
}

// ---------------------------------------------------------------------------
// trsm: tile(i,k) <- tile(i,k) * L_kk^{-T}; split-bf16 panel epilogue.
// (r11/r12-proven verbatim)
// ---------------------------------------------------------------------------
__global__ __launch_bounds__(256) void trsm(float* __restrict__ W,
                                            unsigned short* __restrict__ PH,
                                            unsigned short* __restrict__ PL,
                                            int k) {
  __shared__ float Td[NB][NBP];
  __shared__ float X[NB][NBP];
  __shared__ float dinv_sh[NB];
  int tid = threadIdx.x;
  int i = k + 1 + blockIdx.x;
  int rows = (i == NBLK - 1) ? BSc : NB;
  const float* Gd = W + tile_off(k, k);
  const float* Gx = W + tile_off(i, k);
  for (int idx = tid; idx < TILE_ELEMS / 4; idx += 256) {
    float4 v = ((const float4*)Gd)[idx];
    float4 u = ((const float4*)Gx)[idx];
    int r = idx >> 5, c = (idx & 31) * 4;
    *(float4*)&Td[r][c] = v;
    if (r >= rows) { u.x = 0.0f; u.y = 0.0f; u.z = 0.0f; u.w = 0.0f; }
    *(float4*)&X[r][c] = u;
  }
  __syncthreads();
  if (tid < NB) dinv_sh[tid] = 1.0f / Td[tid][tid];
  __syncthreads();
  int rtile = (tid >> 3) * 4;
  int ctile = (tid & 7) * 4;
#pragma unroll 1
  for (int jb = 0; jb < 4; ++jb) {
    int o = jb * NBB;
    if (jb > 0) {
      float acc[4][4];
#pragma unroll
      for (int m = 0; m < 4; ++m)
#pragma unroll
        for (int n = 0; n < 4; ++n) acc[m][n] = 0.0f;
#pragma unroll 1
      for (int p4 = 0; p4 < (o >> 2); ++p4) {
        float4 a[4], b[4];
#pragma unroll
        for (int m = 0; m < 4; ++m) a[m] = *(const float4*)&X[rtile + m][p4 * 4];
#pragma unroll
        for (int n = 0; n < 4; ++n) b[n] = *(const float4*)&Td[o + ctile + n][p4 * 4];
#pragma unroll
        for (int m = 0; m < 4; ++m)
#pragma unroll
          for (int n = 0; n < 4; ++n)
            acc[m][n] += a[m].x * b[n].x + a[m].y * b[n].y + a[m].z * b[n].z + a[m].w * b[n].w;
      }
#pragma unroll
      for (int m = 0; m < 4; ++m)
#pragma unroll
        for (int n = 0; n < 4; ++n) X[rtile + m][o + ctile + n] -= acc[m][n];
      __syncthreads();
    }
    if (tid < NB) {
      int r = tid;
      float x[NBB];
#pragma unroll
      for (int p4 = 0; p4 < 8; ++p4) {
        float4 v = *(const float4*)&X[r][o + p4 * 4];
        x[p4 * 4] = v.x; x[p4 * 4 + 1] = v.y; x[p4 * 4 + 2] = v.z; x[p4 * 4 + 3] = v.w;
      }
#pragma unroll
      for (int j = 0; j < NBB; ++j) {
        float s = x[j];
#pragma unroll
        for (int p = 0; p < NBB; ++p) {
          if (p < j) s -= x[p] * Td[o + j][o + p];
        }
        x[j] = s * dinv_sh[o + j];
      }
#pragma unroll
      for (int c4 = 0; c4 < 8; ++c4) {
        float4 w; w.x = x[c4 * 4]; w.y = x[c4 * 4 + 1]; w.z = x[c4 * 4 + 2]; w.w = x[c4 * 4 + 3];
        *(float4*)&X[r][o + c4 * 4] = w;
      }
    }
    __syncthreads();
  }
  int r = tid >> 1, hf = tid & 1;
  unsigned short* ph = PH + (size_t)i * TILE_ELEMS + (size_t)r * NB + hf * 64;
  unsigned short* pl = PL + (size_t)i * TILE_ELEMS + (size_t)r * NB + hf * 64;
#pragma unroll 1
  for (int ch = 0; ch < 8; ++ch) {
    unsigned short hb[8], lb[8];
#pragma unroll
    for (int e = 0; e < 8; ++e) {
      float v = X[r][hf * 64 + ch * 8 + e];
      unsigned short h = f2bf(v);
      hb[e] = h;
      lb[e] = f2bf(v - bf2f(h));
    }
    *reinterpret_cast<uint4*>(&ph[ch * 8]) = *reinterpret_cast<const uint4*>(hb);
    *reinterpret_cast<uint4*>(&pl[ch * 8]) = *reinterpret_cast<const uint4*>(lb);
  }
}

// ---------------------------------------------------------------------------
// syrk (fused): tile(i,j) -= P_i P_j^T via split-bf16 MFMA (r12/r14-proven).
// Diagonal WGs (i==j): B operand == A operand (same global pointers), so the
// B-stage is skipped and B-fragments read from Ah/Al (r10-proven pattern).
// WG(0,0) (i=j=k+1, not corner) keeps its update in registers, loads the
// tile into LDS (overlay, 67.7KB — 2 WG/CU), subtracts, runs factor_lds
// under s_setprio(1) (wave-role-diversity regime), stores the lower triangle.
// ---------------------------------------------------------------------------
__global__ __launch_bounds__(256) void syrk(const unsigned short* __restrict__ PH,
                                            const unsigned short* __restrict__ PL,
                                            float* __restrict__ W, int k) {
  int i = k + 1 + blockIdx.x, j = k + 1 + blockIdx.y;
  if (i < j) return;
  bool diag = (i == j);
  __shared__ __align__(16) unsigned char SMEM[SM_SIZE];
  unsigned short (*Ah)[40] = (unsigned short (*)[40])(SMEM);
  unsigned short (*Al)[40] = (unsigned short (*)[40])(SMEM + 10240);
  unsigned short (*Bh)[40] = (unsigned short (*)[40])(SMEM + 20480);
  unsigned short (*Bl)[40] = (unsigned short (*)[40])(SMEM + 30720);
  unsigned short (*BhP)[40] = diag ? Ah : Bh;   // WG-uniform operand redirect
  unsigned short (*BlP)[40] = diag ? Al : Bl;
  const unsigned short* Ahg = PH + (size_t)i * TILE_ELEMS;
  const unsigned short* Alg = PL + (size_t)i * TILE_ELEMS;
  const unsigned short* Bhg = PH + (size_t)j * TILE_ELEMS;
  const unsigned short* Blg = PL + (size_t)j * TILE_ELEMS;
  float* C = W + tile_off(i, j);
  int tid = threadIdx.x, lane = tid & 63, wid = tid >> 6;
  int wr = wid >> 1, wc = wid & 1, lm = lane & 15, lk = lane >> 4;
  f32x4 acc[4][4];
#pragma unroll
  for (int m = 0; m < 4; ++m)
#pragma unroll
    for (int n = 0; n < 4; ++n) acc[m][n] = (f32x4)0.0f;
  int r = tid >> 1, hf = tid & 1;
#pragma unroll 1
  for (int kb = 0; kb < 4; ++kb) {
    int kbase = kb * 32;
    if (kb) __syncthreads();
#pragma unroll
    for (int c = 0; c < 2; ++c) {
      int lc = (hf * 2 + c) * 8;
      int kc = kbase + lc;
      *reinterpret_cast<uint4*>(&Ah[r][lc]) = *reinterpret_cast<const uint4*>(&Ahg[(size_t)r * NB + kc]);
      *reinterpret_cast<uint4*>(&Al[r][lc]) = *reinterpret_cast<const uint4*>(&Alg[(size_t)r * NB + kc]);
      if (!diag) {
        *reinterpret_cast<uint4*>(&Bh[r][lc]) = *reinterpret_cast<const uint4*>(&Bhg[(size_t)r * NB + kc]);
        *reinterpret_cast<uint4*>(&Bl[r][lc]) = *reinterpret_cast<const uint4*>(&Blg[(size_t)r * NB + kc]);
      }
    }
    __syncthreads();
    bf16x8 ah[4], al[4], bh[4], bl[4];
#pragma unroll
    for (int mt = 0; mt < 4; ++mt) {
      int row = wr * 64 + mt * 16 + lm;
      ah[mt] = *reinterpret_cast<const bf16x8*>(&Ah[row][lk * 8]);
      al[mt] = *reinterpret_cast<const bf16x8*>(&Al[row][lk * 8]);
    }
#pragma unroll
    for (int nt = 0; nt < 4; ++nt) {
      int col = wc * 64 + nt * 16 + lm;
      bh[nt] = *reinterpret_cast<const bf16x8*>(&BhP[col][lk * 8]);
      bl[nt] = *reinterpret_cast<const bf16x8*>(&BlP[col][lk * 8]);
    }
#pragma unroll
    for (int mt = 0; mt < 4; ++mt)
#pragma unroll
      for (int nt = 0; nt < 4; ++nt) {
        acc[mt][nt] = __builtin_amdgcn_mfma_f32_16x16x32_bf16(ah[mt], bh[nt], acc[mt][nt], 0, 0, 0);
        acc[mt][nt] = __builtin_amdgcn_mfma_f32_16x16x32_bf16(al[mt], bh[nt], acc[mt][nt], 0, 0, 0);
        acc[mt][nt] = __builtin_amdgcn_mfma_f32_16x16x32_bf16(ah[mt], bl[nt], acc[mt][nt], 0, 0, 0);
      }
  }
  bool dofac = (blockIdx.x == 0 && blockIdx.y == 0 && i < NBLK - 1);
  if (!dofac) {
#pragma unroll
    for (int mt = 0; mt < 4; ++mt)
#pragma unroll
      for (int nt = 0; nt < 4; ++nt) {
#pragma unroll
        for (int q = 0; q < 4; ++q) {
          int rr = wr * 64 + mt * 16 + lk * 4 + q;
          int cc = wc * 64 + nt * 16 + lm;
          C[rr * NB + cc] -= acc[mt][nt][q];
        }
      }
  } else {
    __syncthreads();   // staging LDS reads done; SMEM reusable as T
    float (*T)[NBP] = (float (*)[NBP])SMEM;
    float* dinv_sh = (float*)(SMEM + SM_DINV);
    for (int idx = tid; idx < TILE_ELEMS / 4; idx += 256) {
      float4 v = ((const float4*)C)[idx];
      int rr = idx >> 5, cc = (idx & 31) * 4;
      *(float4*)&T[rr][cc] = v;
    }
    __syncthreads();
#pragma unroll
    for (int mt = 0; mt < 4; ++mt)
#pragma unroll
      for (int nt = 0; nt < 4; ++nt) {
#pragma unroll
        for (int q = 0; q < 4; ++q) {
          int rr = wr * 64 + mt * 16 + lk * 4 + q;
          int cc = wc * 64 + nt * 16 + lm;
          T[rr][cc] -= acc[mt][nt][q];
        }
      }
    __syncthreads();
    __builtin_amdgcn_s_setprio(1);
    factor_lds(T, dinv_sh, tid);
    __builtin_amdgcn_s_setprio(0);
    for (int idx = tid; idx < TILE_ELEMS; idx += 256) {
      int rr = idx >> 7, cc = idx & 127;
      if (cc <= rr) C[idx] = T[rr][cc];
    }
  }
}

// ---------------------------------------------------------------------------
// finalize: -lml from corner trace and diag of L. (r11..r14-proven verbatim)
// ---------------------------------------------------------------------------
__global__ __launch_bounds__(256) void finalize(const float* __restrict__ W,
                                                const int* __restrict__ bsp,
                                                const int* __restrict__ tmaxp,
                                                float* __restrict__ out) {
  __shared__ float rl[4], rq[4];
  int tid = threadIdx.x;
  float lsum = 0.0f;
  for (int d = tid; d < Nn; d += 256) {
    int db = d >> 7, dl = d & 127;
    lsum += logf(W[tile_off(db, db) + (size_t)dl * NB + dl]);
  }
  float qsum = 0.0f;
  if (tid < BSc) qsum = W[tile_off(NBLK - 1, NBLK - 1) + (size_t)tid * NB + tid];
  for (int o = 32; o > 0; o >>= 1) {
    lsum += __shfl_down(lsum, o, 64);
    qsum += __shfl_down(qsum, o, 64);
  }
  int lane = tid & 63, wid = tid >> 6;
  if (lane == 0) { rl[wid] = lsum; rq[wid] = qsum; }
  __syncthreads();
  if (tid == 0) {
    float Lt = rl[0] + rl[1] + rl[2] + rl[3];
    float Qt = rq[0] + rq[1] + rq[2] + rq[3];
    float bsf = (float)bsp[0];
    float tmaxf = (float)tmaxp[0];
    out[0] = -Qt / (2.0f * bsf) + Lt + 0.5f * tmaxf * logf(6.283185307179586f);
  }
}

extern "C" void kernel_launch(void* const* d_in, const int* in_sizes, int n_in,
                              void* d_out, int out_size, void* d_ws, size_t ws_size,
                              hipStream_t stream) {
  const float* Y   = (const float*)d_in[0];
  const float* mu  = (const float*)d_in[1];
  const float* Kp  = (const float*)d_in[2];
  const float* Sg  = (const float*)d_in[3];
  const int*   bsp = (const int*)d_in[4];
  const int*   tmp_= (const int*)d_in[5];
  float* W = (float*)d_ws;                                                  // 36.8 MB
  unsigned short* PH = (unsigned short*)(W + (size_t)NTILES * TILE_ELEMS);  // 33 tiles bf16 hi
  unsigned short* PL = PH + (size_t)NBLK * TILE_ELEMS;                      // 33 tiles bf16 lo
  float* out = (float*)d_out;

  prep<<<NTILES, 256, 0, stream>>>(Y, mu, Kp, Sg, W);
  potf2<<<1, 256, 0, stream>>>(W, 0);   // one-shot: factor tile(0,0)

  for (int k = 0; k < NK; ++k) {
    int T = NBLK - (k + 1);
    trsm<<<T, 256, 0, stream>>>(W, PH, PL, k);
    dim3 g(T, T);
    syrk<<<g, 256, 0, stream>>>(PH, PL, W, k);   // WG(0,0) also factors tile(k+1,k+1)
  }
  finalize<<<1, 256, 0, stream>>>(W, bsp, tmp_, out);
}